// Round 1
// baseline (1731.519 us; speedup 1.0000x reference)
//
#include <hip/hip_runtime.h>

// Sparse SGD: weights_out = weights; for i < valid_count:
//   weights_out[indices[i]] -= lr * gradients[i]  (scatter-add, duplicates accumulate)
// moments_out = moments (pass-through).
//
// Phase 1: bulk D2D copies weights->out, moments->out+VD (memcpy nodes, near-HBM-BW).
// Phase 2: atomic scatter of -lr*g into the weights copy (device-scope atomicAdd
//          handles duplicate indices across XCDs).

#define D_DIM 128

__global__ void sgd_scatter_kernel(const float* __restrict__ grads,
                                   const int* __restrict__ indices,
                                   const float* __restrict__ lr_ptr,
                                   const int* __restrict__ vc_ptr,
                                   float* __restrict__ w_out) {
    const float lr = lr_ptr[0];                         // scalar, L1-cached broadcast
    const long long total = (long long)vc_ptr[0] * D_DIM;
    const long long stride = (long long)gridDim.x * blockDim.x;
    for (long long t = (long long)blockIdx.x * blockDim.x + threadIdx.x;
         t < total; t += stride) {
        const int i = (int)(t >> 7);        // gradient row
        const int j = (int)(t & 127);       // column
        const long long row = (long long)indices[i];
        atomicAdd(w_out + row * D_DIM + j, -lr * grads[t]);
    }
}

extern "C" void kernel_launch(void* const* d_in, const int* in_sizes, int n_in,
                              void* d_out, int out_size, void* d_ws, size_t ws_size,
                              hipStream_t stream) {
    const float* grads   = (const float*)d_in[0];   // [N, 128] fp32
    const float* weights = (const float*)d_in[1];   // [V, 128] fp32
    const float* moments = (const float*)d_in[2];   // [V, 128] fp32
    const int*   indices = (const int*)  d_in[3];   // [N] int32
    const float* lr_ptr  = (const float*)d_in[4];   // [1] fp32
    const int*   vc_ptr  = (const int*)  d_in[5];   // [1] int (static 200000)

    const size_t VD = (size_t)in_sizes[1];          // V * 128 elements
    float* w_out = (float*)d_out;
    float* m_out = w_out + VD;

    // Phase 1: pass-through copies (graph-capture-safe async D2D).
    hipMemcpyAsync(w_out, weights, VD * sizeof(float), hipMemcpyDeviceToDevice, stream);
    hipMemcpyAsync(m_out, moments, VD * sizeof(float), hipMemcpyDeviceToDevice, stream);

    // Phase 2: scatter-add the valid gradient rows into the weights copy.
    // Grid-stride: 8192 blocks x 256 threads covers 25.6M elements in ~12 iters/thread.
    const int blocks = 8192, threads = 256;
    sgd_scatter_kernel<<<blocks, threads, 0, stream>>>(grads, indices, lr_ptr, vc_ptr, w_out);
}